// Round 1
// baseline (217.201 us; speedup 1.0000x reference)
//
#include <hip/hip_runtime.h>
#include <hip/hip_bf16.h>

typedef __attribute__((ext_vector_type(8))) short bf16x8;
typedef __attribute__((ext_vector_type(4))) float f32x4;

#define NKT1 19  // k-tiles for layer 1 (K=580 padded to 608)

__device__ inline ushort f2bf(float f) {
    union { float f; unsigned u; } x; x.f = f;
    unsigned u = x.u;
    u += 0x7fffu + ((u >> 16) & 1u);   // round-to-nearest-even
    return (ushort)(u >> 16);
}

// feat (B,C,H,W) f32 -> featT (B,H,W,C) bf16
__global__ void prep_feat_k(const float* __restrict__ feat, ushort* __restrict__ featT) {
    int idx = blockIdx.x * 256 + threadIdx.x;
    if (idx >= 2 * 96 * 96 * 64) return;
    int c = idx & 63;
    int rest = idx >> 6;
    int x = rest % 96; rest /= 96;
    int y = rest % 96;
    int b = rest / 96;
    featT[idx] = f2bf(feat[((b * 64 + c) * 96 + y) * 96 + x]);
}

// Weights f32 (K,N) -> bf16 B-fragment layout [nt][kt][lane][8]
// mode 0: layer-1 with k-permutation (k = tap*64+c  <-  src row c*9+tap), K=580 pad 608
// mode 1: plain K=256
// mode 2: W4 (256,1), N padded to 16 (cols 1..15 zero)
__global__ void prep_w_k(const float* __restrict__ W, ushort* __restrict__ Wp,
                         int NT, int NKT, int Nstride, int mode) {
    int idx = blockIdx.x * 256 + threadIdx.x;
    if (idx >= NT * NKT * 64) return;
    int lane = idx & 63;
    int kt = (idx >> 6) % NKT;
    int nt = idx / (64 * NKT);
    int n = nt * 16 + (lane & 15);
    int kbase = kt * 32 + (lane >> 4) * 8;
    ushort o[8];
    #pragma unroll
    for (int i = 0; i < 8; ++i) {
        int k = kbase + i;
        float v = 0.0f;
        if (mode == 0) {
            if (k < 576) { int tap = k >> 6, c = k & 63; v = W[(c * 9 + tap) * Nstride + n]; }
            else if (k < 580) v = W[k * Nstride + n];
        } else if (mode == 1) {
            v = W[k * Nstride + n];
        } else {
            v = (n == 0) ? W[k] : 0.0f;
        }
        o[i] = f2bf(v);
    }
    *reinterpret_cast<uint4*>(Wp + (size_t)idx * 8) = *reinterpret_cast<const uint4*>(o);
}

template<int NKT>
__device__ inline void run_layer(const ushort* __restrict__ Wp,
                                 const float* __restrict__ bias,
                                 const ushort* A_lds, int lane, int w,
                                 f32x4 (&acc)[4][4]) {
    float bv[4];
    #pragma unroll
    for (int ct = 0; ct < 4; ++ct) bv[ct] = bias[(w * 4 + ct) * 16 + (lane & 15)];
    #pragma unroll
    for (int rt = 0; rt < 4; ++rt)
        #pragma unroll
        for (int ct = 0; ct < 4; ++ct) {
            acc[rt][ct][0] = bv[ct]; acc[rt][ct][1] = bv[ct];
            acc[rt][ct][2] = bv[ct]; acc[rt][ct][3] = bv[ct];
        }
    const int swl = lane ^ ((lane >> 3) & 3);
    for (int kt = 0; kt < NKT; ++kt) {
        bf16x8 a[4], b[4];
        #pragma unroll
        for (int rt = 0; rt < 4; ++rt)
            a[rt] = *reinterpret_cast<const bf16x8*>(A_lds + ((rt * NKT1 + kt) * 64 + swl) * 8);
        #pragma unroll
        for (int ct = 0; ct < 4; ++ct)
            b[ct] = *reinterpret_cast<const bf16x8*>(Wp + (((size_t)(w * 4 + ct) * NKT + kt) * 64 + lane) * 8);
        #pragma unroll
        for (int rt = 0; rt < 4; ++rt)
            #pragma unroll
            for (int ct = 0; ct < 4; ++ct)
                acc[rt][ct] = __builtin_amdgcn_mfma_f32_16x16x32_bf16(a[rt], b[ct], acc[rt][ct], 0, 0, 0);
    }
}

__device__ inline void store_acts(const f32x4 (&acc)[4][4], ushort* A_lds, int lane, int w) {
    #pragma unroll
    for (int rt = 0; rt < 4; ++rt)
        #pragma unroll
        for (int ct = 0; ct < 4; ++ct) {
            int col = (w * 4 + ct) * 16 + (lane & 15);
            int kt = col >> 5;
            int chk = (col & 31) >> 3;
            #pragma unroll
            for (int j = 0; j < 4; ++j) {
                int rowm = ((lane >> 4) << 2) + j;
                int slot = rowm + (chk << 4);
                int sw = slot ^ ((slot >> 3) & 3);
                A_lds[((rt * NKT1 + kt) * 64 + sw) * 8 + (col & 7)] =
                    f2bf(fmaxf(acc[rt][ct][j], 0.0f));
            }
        }
}

__global__ __launch_bounds__(256, 2) void liif_main(
    const float* __restrict__ coord, const float* __restrict__ cell,
    const ushort* __restrict__ featT,
    const ushort* __restrict__ W0p, const ushort* __restrict__ W1p,
    const ushort* __restrict__ W2p, const ushort* __restrict__ W3p,
    const ushort* __restrict__ W4p,
    const float* __restrict__ b0, const float* __restrict__ b1,
    const float* __restrict__ b2, const float* __restrict__ b3,
    const float* __restrict__ b4, float* __restrict__ out)
{
    __shared__ ushort A_lds[4 * NKT1 * 64 * 8];   // 77824 B
    __shared__ float pred_lds[64];
    __shared__ float area_lds[64];

    const int t = threadIdx.x;
    const int lane = t & 63;
    const int w = t >> 6;

    // ---------------- gather: build A (64 rows x 608) in fragment layout ----------------
    {
        const int r = t >> 2, sub = t & 3;          // 4 threads per row
        const int qi = r >> 2, s = r & 3;           // row = 4*qi + shift
        const int gq = blockIdx.x * 16 + qi;        // = b*Q + q
        const int b = gq >> 15;                     // Q = 32768
        const float vx = (s & 2) ? 1.0f : -1.0f;
        const float vy = (s & 1) ? 1.0f : -1.0f;
        const float rxf = (float)(1.0 / 96.0);
        const float lo = (float)(-1.0 + 1e-6);
        const float hi = (float)(1.0 - 1e-6);
        float c0 = coord[gq * 2 + 0], c1 = coord[gq * 2 + 1];
        float cl0 = cell[gq * 2 + 0], cl1 = cell[gq * 2 + 1];
        float sc0 = fminf(fmaxf(__fadd_rn(__fadd_rn(c0, vx * rxf), 1e-6f), lo), hi);
        float sc1 = fminf(fmaxf(__fadd_rn(__fadd_rn(c1, vy * rxf), 1e-6f), lo), hi);
        // ((g+1)*96 - 1)*0.5, unfused f32 to match jnp exactly, then round-half-even
        float fy = __fmul_rn(__fadd_rn(__fmul_rn(__fadd_rn(sc0, 1.0f), 96.0f), -1.0f), 0.5f);
        float fx = __fmul_rn(__fadd_rn(__fmul_rn(__fadd_rn(sc1, 1.0f), 96.0f), -1.0f), 0.5f);
        int iy = (int)rintf(fy); iy = iy < 0 ? 0 : (iy > 95 ? 95 : iy);
        int ix = (int)rintf(fx); ix = ix < 0 ? 0 : (ix > 95 ? 95 : ix);
        float qc0 = (iy + 0.5f) * (float)(2.0 / 96.0) - 1.0f;
        float qc1 = (ix + 0.5f) * (float)(2.0 / 96.0) - 1.0f;
        float rel0 = (c0 - qc0) * 96.0f;
        float rel1 = (c1 - qc1) * 96.0f;
        if (sub == 0) area_lds[r] = fabsf(rel0 * rel1) + 1e-9f;

        const int rt = r >> 4;
        const int slot = (r & 15) + (sub << 4);
        const int sw = slot ^ ((slot >> 3) & 3);
        const ushort* fb = featT + (size_t)b * 96 * 96 * 64;
        #pragma unroll
        for (int i = 0; i < 18; ++i) {
            int j = (i << 2) + sub;      // chunk 0..71: k = 8j.., tap = j>>3, c0 = (j&7)*8
            int tap = j >> 3;
            int cc = (j & 7) << 3;
            int yy = iy + (tap / 3) - 1;
            int xx = ix + (tap % 3) - 1;
            uint4 val = make_uint4(0, 0, 0, 0);
            if (yy >= 0 && yy < 96 && xx >= 0 && xx < 96)
                val = *reinterpret_cast<const uint4*>(fb + ((yy * 96 + xx) * 64 + cc));
            *reinterpret_cast<uint4*>(&A_lds[((rt * NKT1 + i) * 64 + sw) * 8]) = val;
        }
        {   // k-tile 18: extras (rel0, rel1, rel_cell) + zero padding
            ushort ex[8] = {0, 0, 0, 0, 0, 0, 0, 0};
            if (sub == 0) {
                ex[0] = f2bf(rel0); ex[1] = f2bf(rel1);
                ex[2] = f2bf(cl0 * 96.0f); ex[3] = f2bf(cl1 * 96.0f);
            }
            *reinterpret_cast<uint4*>(&A_lds[((rt * NKT1 + 18) * 64 + sw) * 8]) =
                *reinterpret_cast<const uint4*>(ex);
        }
    }
    __syncthreads();

    f32x4 acc[4][4];
    run_layer<NKT1>(W0p, b0, A_lds, lane, w, acc);
    __syncthreads();
    store_acts(acc, A_lds, lane, w);
    __syncthreads();
    run_layer<8>(W1p, b1, A_lds, lane, w, acc);
    __syncthreads();
    store_acts(acc, A_lds, lane, w);
    __syncthreads();
    run_layer<8>(W2p, b2, A_lds, lane, w, acc);
    __syncthreads();
    store_acts(acc, A_lds, lane, w);
    __syncthreads();
    run_layer<8>(W3p, b3, A_lds, lane, w, acc);
    __syncthreads();
    store_acts(acc, A_lds, lane, w);
    __syncthreads();

    // ---------------- layer 5: 256 -> 1 (N padded to 16, col 0 valid) ----------------
    if (w == 0) {
        float b4v = b4[0];
        f32x4 a5[4];
        #pragma unroll
        for (int rt = 0; rt < 4; ++rt) { a5[rt][0] = b4v; a5[rt][1] = b4v; a5[rt][2] = b4v; a5[rt][3] = b4v; }
        const int swl = lane ^ ((lane >> 3) & 3);
        for (int kt = 0; kt < 8; ++kt) {
            bf16x8 bb = *reinterpret_cast<const bf16x8*>(W4p + ((size_t)kt * 64 + lane) * 8);
            #pragma unroll
            for (int rt = 0; rt < 4; ++rt) {
                bf16x8 aa = *reinterpret_cast<const bf16x8*>(A_lds + ((rt * NKT1 + kt) * 64 + swl) * 8);
                a5[rt] = __builtin_amdgcn_mfma_f32_16x16x32_bf16(aa, bb, a5[rt], 0, 0, 0);
            }
        }
        if ((lane & 15) == 0) {
            #pragma unroll
            for (int rt = 0; rt < 4; ++rt)
                #pragma unroll
                for (int j = 0; j < 4; ++j)
                    pred_lds[rt * 16 + ((lane >> 4) << 2) + j] = a5[rt][j];
        }
    }
    __syncthreads();

    // ---------------- local-ensemble combine (diagonal area swap) ----------------
    if (t < 16) {
        int gq = blockIdx.x * 16 + t;
        float p0 = pred_lds[t * 4 + 0], p1 = pred_lds[t * 4 + 1];
        float p2 = pred_lds[t * 4 + 2], p3 = pred_lds[t * 4 + 3];
        float a0 = area_lds[t * 4 + 0], a1 = area_lds[t * 4 + 1];
        float a2 = area_lds[t * 4 + 2], a3 = area_lds[t * 4 + 3];
        float tot = a0 + a1 + a2 + a3;
        out[gq] = (p0 * a3 + p1 * a2 + p2 * a1 + p3 * a0) / tot;
    }
}

extern "C" void kernel_launch(void* const* d_in, const int* in_sizes, int n_in,
                              void* d_out, int out_size, void* d_ws, size_t ws_size,
                              hipStream_t stream) {
    const float* feat  = (const float*)d_in[0];
    const float* coord = (const float*)d_in[1];
    const float* cell  = (const float*)d_in[2];
    const float* W0 = (const float*)d_in[3];
    const float* b0 = (const float*)d_in[4];
    const float* W1 = (const float*)d_in[5];
    const float* b1 = (const float*)d_in[6];
    const float* W2 = (const float*)d_in[7];
    const float* b2 = (const float*)d_in[8];
    const float* W3 = (const float*)d_in[9];
    const float* b3 = (const float*)d_in[10];
    const float* W4 = (const float*)d_in[11];
    const float* b4 = (const float*)d_in[12];
    float* out = (float*)d_out;

    ushort* featT = (ushort*)d_ws;          // 2*96*96*64      = 1179648 elems
    ushort* W0p = featT + 1179648;          // 16*19*64*8      = 155648
    ushort* W1p = W0p + 155648;             // 16*8*64*8       = 65536
    ushort* W2p = W1p + 65536;
    ushort* W3p = W2p + 65536;
    ushort* W4p = W3p + 65536;              // 1*8*64*8        = 4096
    // total ws usage: 3,072,000 bytes

    prep_feat_k<<<4608, 256, 0, stream>>>(feat, featT);
    prep_w_k<<<76, 256, 0, stream>>>(W0, W0p, 16, 19, 256, 0);
    prep_w_k<<<32, 256, 0, stream>>>(W1, W1p, 16, 8, 256, 1);
    prep_w_k<<<32, 256, 0, stream>>>(W2, W2p, 16, 8, 256, 1);
    prep_w_k<<<32, 256, 0, stream>>>(W3, W3p, 16, 8, 256, 1);
    prep_w_k<<<2, 256, 0, stream>>>(W4, W4p, 1, 8, 1, 2);
    liif_main<<<4096, 256, 0, stream>>>(coord, cell, featT, W0p, W1p, W2p, W3p, W4p,
                                        b0, b1, b2, b3, b4, out);
}